// Round 17
// baseline (683.665 us; speedup 1.0000x reference)
//
#include <hip/hip_runtime.h>
#include <hip/hip_bf16.h>
#include <math.h>

constexpr int B  = 4;
constexpr int S  = 2048;
constexpr int D  = 1024;
constexpr int H  = 16;
constexpr int HD = 64;
constexpr float LOG2E  = 1.4426950408889634f;
constexpr float SCALE2 = 0.125f * LOG2E;   // fold 1/sqrt(64) and log2(e)

using f32x4 = __attribute__((ext_vector_type(4))) float;
using s16x8 = __attribute__((ext_vector_type(8))) short;
using u16x8 = __attribute__((ext_vector_type(8))) unsigned short;
using u16x4 = __attribute__((ext_vector_type(4))) unsigned short;

__device__ __forceinline__ unsigned short f2bf(float f) {
    union { float f; unsigned u; } x; x.f = f;
    unsigned r = x.u + 0x7fffu + ((x.u >> 16) & 1u);
    return (unsigned short)(r >> 16);
}
__device__ __forceinline__ unsigned short f2bf_fast(float f) {
    union { float f; unsigned u; } x; x.f = f;
    return (unsigned short)((x.u + 0x8000u) >> 16);
}
__device__ __forceinline__ float bf2f(unsigned short h) {
    union { unsigned u; float f; } x; x.u = ((unsigned)h) << 16;
    return x.f;
}
__device__ __forceinline__ float fexp2(float x) {
#if __has_builtin(__builtin_amdgcn_exp2f)
    return __builtin_amdgcn_exp2f(x);
#else
    return __expf(x * 0.6931471805599453f);
#endif
}

#define MFMA_BF16(Af, Bf, Cf) __builtin_amdgcn_mfma_f32_16x16x32_bf16(Af, Bf, Cf, 0, 0, 0)

// ---------------------------------------------------------------------------
// Prep stage 1: (a) q/k/v f32->bf16, (b) weight transpose+convert.
// NT loads on dead f32 sources. Blocks: [0,6144) cvt, [6144,6912) wt.
// ---------------------------------------------------------------------------
__global__ __launch_bounds__(256) void k_prep(
    const float* __restrict__ Xq, const float* __restrict__ Xk,
    const float* __restrict__ Xv,
    unsigned short* __restrict__ qb, unsigned short* __restrict__ kb,
    unsigned short* __restrict__ vb,
    const float* __restrict__ Wq, const float* __restrict__ Wk,
    const float* __restrict__ Wv,
    unsigned short* __restrict__ wqt, unsigned short* __restrict__ wkt,
    unsigned short* __restrict__ wvt) {
    __shared__ unsigned short T[64][68];
    const int bid = blockIdx.x;
    const int t = threadIdx.x;

    if (bid < 6144) {
        const int op = bid >> 11, xb = bid & 2047;
        const float* X = op == 0 ? Xq : (op == 1 ? Xk : Xv);
        unsigned short* O = op == 0 ? qb : (op == 1 ? kb : vb);
        const size_t N = (size_t)B * S * D;
        const size_t stride = (size_t)2048 * 256 * 8;
        for (size_t i = ((size_t)xb * 256 + t) * 8; i < N; i += stride) {
            f32x4 a0 = __builtin_nontemporal_load(reinterpret_cast<const f32x4*>(&X[i]));
            f32x4 a1 = __builtin_nontemporal_load(reinterpret_cast<const f32x4*>(&X[i + 4]));
            u16x8 o;
#pragma unroll
            for (int j = 0; j < 4; ++j) { o[j] = f2bf(a0[j]); o[4 + j] = f2bf(a1[j]); }
            *reinterpret_cast<u16x8*>(&O[i]) = o;
        }
    } else {
        const int idx = bid - 6144;
        const int op = idx >> 8, r = idx & 255;
        const float* W = op == 0 ? Wq : (op == 1 ? Wk : Wv);
        unsigned short* Wt = op == 0 ? wqt : (op == 1 ? wkt : wvt);
        const int k0 = (r & 15) * 64, n0 = (r >> 4) * 64;
        {
            const int kr = t >> 4, nc4 = (t & 15) * 4;
            for (int rr = 0; rr < 4; ++rr) {
                const int kk = kr + rr * 16;
                f32x4 wv = __builtin_nontemporal_load(
                    reinterpret_cast<const f32x4*>(&W[(size_t)(k0 + kk) * D + n0 + nc4]));
#pragma unroll
                for (int j = 0; j < 4; ++j) T[nc4 + j][kk] = f2bf(wv[j]);
            }
        }
        __syncthreads();
        {
            const int nr = t >> 4, kc4 = (t & 15) * 4;
            for (int rr = 0; rr < 4; ++rr) {
                const int nn = nr + rr * 16;
                u16x4 o;
#pragma unroll
                for (int j = 0; j < 4; ++j) o[j] = T[nn][kc4 + j];
                *reinterpret_cast<u16x4*>(&Wt[(size_t)(n0 + nn) * D + k0 + kc4]) = o;
            }
        }
    }
}

// ---------------------------------------------------------------------------
// Prep stage 2, merged with projections: flat 11264-block grid, interleaved
// 3 proj : 8 abf per 11-block group so the alibi f32->bf16 HBM stream hides
// under the MFMA/LDS-bound projection compute (no data dependency).
//   proj idx [0,3072): op = idx>>10 (0=q,1=k,2=v), r = idx&1023,
//                      bn = (r&7)*128, bm = (r>>3)*128.
//   abf  idx [0,8192): grid-stride convert, log2e-prescaled.
// ---------------------------------------------------------------------------
__global__ __launch_bounds__(256) void k_projabf(
    const unsigned short* __restrict__ qb, const unsigned short* __restrict__ kb,
    const unsigned short* __restrict__ vb,
    const unsigned short* __restrict__ wqt, const unsigned short* __restrict__ wkt,
    const unsigned short* __restrict__ wvt,
    unsigned short* __restrict__ qh, unsigned short* __restrict__ kh,
    unsigned short* __restrict__ vT,
    const float* __restrict__ ALIBI, unsigned short* __restrict__ ABF,
    int do_abf) {
    __shared__ alignas(16) unsigned short SM[2][128][72];
    const int bid = blockIdx.x;
    const int t = threadIdx.x;
    const int sel = bid % 11;

    if (sel < 3) {
        const int pidx = (bid / 11) * 3 + sel;       // [0,3072) bijective
        const int op = pidx >> 10;                   // 0=q, 1=k, 2=v
        const int r  = pidx & 1023;
        const int bn = (r & 7) * 128, bm = (r >> 3) * 128;
        const unsigned short* X  = op == 0 ? qb : (op == 1 ? kb : vb);
        const unsigned short* Wt = op == 0 ? wqt : (op == 1 ? wkt : wvt);
        unsigned short (*As)[72] = SM[0];
        unsigned short (*Bs)[72] = SM[1];
        const int w = t >> 6, l = t & 63;
        const int wr = w >> 1, wc = w & 1;
        const int lr = l & 15, lg = l >> 4;
        f32x4 acc[4][4] = {};

        for (int k0 = 0; k0 < D; k0 += 64) {
            for (int i = 0; i < 4; ++i) {
                const int idx = t + i * 256;
                const int row = idx >> 3, c8 = (idx & 7) * 8;
                *reinterpret_cast<u16x8*>(&As[row][c8]) =
                    *reinterpret_cast<const u16x8*>(&X[(size_t)(bm + row) * D + k0 + c8]);
                *reinterpret_cast<u16x8*>(&Bs[row][c8]) =
                    *reinterpret_cast<const u16x8*>(&Wt[(size_t)(bn + row) * D + k0 + c8]);
            }
            __syncthreads();
#pragma unroll
            for (int kk = 0; kk < 2; ++kk) {
                s16x8 af[4], bf[4];
#pragma unroll
                for (int f = 0; f < 4; ++f) {
                    af[f] = *reinterpret_cast<const s16x8*>(&As[wr * 64 + f * 16 + lr][kk * 32 + lg * 8]);
                    bf[f] = *reinterpret_cast<const s16x8*>(&Bs[wc * 64 + f * 16 + lr][kk * 32 + lg * 8]);
                }
#pragma unroll
                for (int fm = 0; fm < 4; ++fm)
#pragma unroll
                    for (int fn = 0; fn < 4; ++fn)
                        acc[fm][fn] = MFMA_BF16(af[fm], bf[fn], acc[fm][fn]);
            }
            __syncthreads();
        }

        if (op < 2) {
            unsigned short* Y = op == 0 ? qh : kh;
#pragma unroll
            for (int fm = 0; fm < 4; ++fm)
#pragma unroll
                for (int fn = 0; fn < 4; ++fn)
#pragma unroll
                    for (int rr = 0; rr < 4; ++rr) {
                        const int m = bm + wr * 64 + fm * 16 + lg * 4 + rr;
                        const int n = bn + wc * 64 + fn * 16 + lr;
                        const int b = m >> 11, s = m & (S - 1);
                        const int h = n >> 6, e = n & 63;
                        Y[(((size_t)(b * H + h) * S) + s) * HD + e] = f2bf(acc[fm][fn][rr]);
                    }
        } else {
            unsigned short (*T)[144] = reinterpret_cast<unsigned short(*)[144]>(&SM[0][0][0]);
#pragma unroll
            for (int fm = 0; fm < 4; ++fm)
#pragma unroll
                for (int fn = 0; fn < 4; ++fn)
#pragma unroll
                    for (int rr = 0; rr < 4; ++rr)
                        T[wc * 64 + fn * 16 + lr][wr * 64 + fm * 16 + lg * 4 + rr] =
                            f2bf(acc[fm][fn][rr]);
            __syncthreads();
            const int b = bm >> 11, s0 = bm & (S - 1);
            for (int it = 0; it < 8; ++it) {
                const int idx = t + it * 256;
                const int row = idx >> 4, c8 = (idx & 15) * 8;
                const int h = (bn + row) >> 6, e = (bn + row) & 63;
                *reinterpret_cast<u16x8*>(&vT[((size_t)(b * H + h) * HD + e) * S + s0 + c8]) =
                    *reinterpret_cast<const u16x8*>(&T[row][c8]);
            }
        }
    } else {
        if (!do_abf) return;
        const int aidx = (bid / 11) * 8 + (sel - 3);  // [0,8192) bijective
        const size_t N = (size_t)H * S * S;
        const size_t stride = (size_t)8192 * 256 * 8;
        for (size_t i = ((size_t)aidx * 256 + t) * 8; i < N; i += stride) {
            f32x4 a0 = __builtin_nontemporal_load(reinterpret_cast<const f32x4*>(&ALIBI[i]));
            f32x4 a1 = __builtin_nontemporal_load(reinterpret_cast<const f32x4*>(&ALIBI[i + 4]));
            u16x8 o;
#pragma unroll
            for (int j = 0; j < 4; ++j) {
                o[j]     = f2bf(a0[j] * LOG2E);
                o[4 + j] = f2bf(a1[j] * LOG2E);
            }
            *reinterpret_cast<u16x8*>(&ABF[i]) = o;
        }
    }
}

// ---------------------------------------------------------------------------
// Pass 1 (swapped QK^T): invl[b,h,q] = 1/sum_k exp2(score2).
// 1024 blocks, XCD-chunked: each XCD owns 8 consecutive bh (K/Q L2-resident).
// ---------------------------------------------------------------------------
template <bool ABF16>
__global__ __launch_bounds__(512, 4) void k_sumexp(
    const unsigned short* __restrict__ QH, const unsigned short* __restrict__ KH,
    const float* __restrict__ ALIBI, const unsigned short* __restrict__ ABF,
    const int* __restrict__ MASK, float* __restrict__ INVL) {
    __shared__ alignas(16) unsigned short Ks[64][72];
    __shared__ alignas(16) unsigned short ALs[128][72];

    const int bid = blockIdx.x;
    const int wg = (bid & 7) * 128 + (bid >> 3);   // XCD-chunked (1024 % 8 == 0)
    const int bh = wg >> 4, b = bh >> 4, h = bh & 15;
    const int q0 = (wg & 15) * 128;
    const int t = threadIdx.x, w = t >> 6, ln = t & 63;
    const int lr = ln & 15, lg = ln >> 4;
    const unsigned short NEGBIG = f2bf(-1e30f);
    const size_t hoff = (size_t)h * S * S;

    const unsigned short* Kb = KH + (size_t)bh * S * HD;

    s16x8 qf[2];
#pragma unroll
    for (int kk = 0; kk < 2; ++kk)
        qf[kk] = *reinterpret_cast<const s16x8*>(
            &QH[((size_t)bh * S + q0 + w * 16 + lr) * HD + kk * 32 + lg * 8]);

    float psum = 0.f;

    for (int k0 = 0; k0 < S; k0 += 64) {
        {
            const int row = t >> 3, c8 = (t & 7) * 8;
            *reinterpret_cast<u16x8*>(&Ks[row][c8]) =
                *reinterpret_cast<const u16x8*>(&Kb[(size_t)(k0 + row) * HD + c8]);
        }
#pragma unroll
        for (int i = 0; i < 2; ++i) {
            const int idx = t + i * 512, row = idx >> 3, c8 = (idx & 7) * 8;
            int4 m0 = *reinterpret_cast<const int4*>(&MASK[b * S + k0 + c8]);
            int4 m1 = *reinterpret_cast<const int4*>(&MASK[b * S + k0 + c8 + 4]);
            u16x8 av;
            if constexpr (ABF16) {
                av = *reinterpret_cast<const u16x8*>(&ABF[hoff + (size_t)(q0 + row) * S + k0 + c8]);
            } else {
                f32x4 a0 = *reinterpret_cast<const f32x4*>(&ALIBI[hoff + (size_t)(q0 + row) * S + k0 + c8]);
                f32x4 a1 = *reinterpret_cast<const f32x4*>(&ALIBI[hoff + (size_t)(q0 + row) * S + k0 + c8 + 4]);
#pragma unroll
                for (int j = 0; j < 4; ++j) {
                    av[j] = f2bf(a0[j] * LOG2E);
                    av[4 + j] = f2bf(a1[j] * LOG2E);
                }
            }
            u16x8 sv;
            sv[0] = m0.x ? NEGBIG : av[0];
            sv[1] = m0.y ? NEGBIG : av[1];
            sv[2] = m0.z ? NEGBIG : av[2];
            sv[3] = m0.w ? NEGBIG : av[3];
            sv[4] = m1.x ? NEGBIG : av[4];
            sv[5] = m1.y ? NEGBIG : av[5];
            sv[6] = m1.z ? NEGBIG : av[6];
            sv[7] = m1.w ? NEGBIG : av[7];
            *reinterpret_cast<u16x8*>(&ALs[row][c8]) = sv;
        }
        __syncthreads();

        f32x4 acc[4] = {};
#pragma unroll
        for (int kk = 0; kk < 2; ++kk)
#pragma unroll
            for (int fn = 0; fn < 4; ++fn) {
                s16x8 kf = *reinterpret_cast<const s16x8*>(&Ks[fn * 16 + lr][kk * 32 + lg * 8]);
                acc[fn] = MFMA_BF16(kf, qf[kk], acc[fn]);   // SWAPPED: lane = q-row lr
            }
#pragma unroll
        for (int fn = 0; fn < 4; ++fn) {
            u16x4 alv = *reinterpret_cast<const u16x4*>(&ALs[w * 16 + lr][fn * 16 + lg * 4]);
            f32x4 al;
#pragma unroll
            for (int j = 0; j < 4; ++j) al[j] = bf2f(alv[j]);
            f32x4 sv = acc[fn] * SCALE2 + al;
            psum += fexp2(sv[0]) + fexp2(sv[1]) + fexp2(sv[2]) + fexp2(sv[3]);
        }
        __syncthreads();
    }

    psum += __shfl_xor(psum, 16, 64);
    psum += __shfl_xor(psum, 32, 64);
    if (lg == 0)
        INVL[(size_t)bh * S + q0 + w * 16 + lr] = 1.0f / psum;
}

// ---------------------------------------------------------------------------
// Pass 2 (swapped QK^T): p -> `a` (f32x4 NT stores from regs) + PV -> out.
// Ps aliases ALs (each slot read+rewritten by the same lane). XCD-chunked.
// ---------------------------------------------------------------------------
template <bool ABF16>
__global__ __launch_bounds__(512, 4) void k_attn(
    const unsigned short* __restrict__ QH, const unsigned short* __restrict__ KH,
    const unsigned short* __restrict__ VT, const float* __restrict__ ALIBI,
    const unsigned short* __restrict__ ABF, const int* __restrict__ MASK,
    const float* __restrict__ INVL, float* __restrict__ Aout,
    float* __restrict__ OUT) {
    __shared__ alignas(16) unsigned short Ks[64][72];
    __shared__ alignas(16) unsigned short Vs[64][72];
    __shared__ alignas(16) unsigned short ALs[128][72];   // alibi tile, then P (aliased)

    const int bid = blockIdx.x;
    const int wg = (bid & 7) * 128 + (bid >> 3);   // XCD-chunked
    const int bh = wg >> 4, b = bh >> 4, h = bh & 15;
    const int q0 = (wg & 15) * 128;
    const int t = threadIdx.x, w = t >> 6, ln = t & 63;
    const int lr = ln & 15, lg = ln >> 4;
    const unsigned short NEGBIG = f2bf(-1e30f);
    const size_t hoff = (size_t)h * S * S;

    const unsigned short* Kb = KH + (size_t)bh * S * HD;
    const unsigned short* Vb = VT + (size_t)bh * HD * S;

    s16x8 qf[2];
#pragma unroll
    for (int kk = 0; kk < 2; ++kk)
        qf[kk] = *reinterpret_cast<const s16x8*>(
            &QH[((size_t)bh * S + q0 + w * 16 + lr) * HD + kk * 32 + lg * 8]);

    const float invl = INVL[(size_t)bh * S + q0 + w * 16 + lr];
    float* arow = Aout + ((size_t)bh * S + q0 + w * 16 + lr) * S;

    f32x4 oacc[4] = {};

    for (int k0 = 0; k0 < S; k0 += 64) {
        {
            const int row = t >> 3, c8 = (t & 7) * 8;
            *reinterpret_cast<u16x8*>(&Ks[row][c8]) =
                *reinterpret_cast<const u16x8*>(&Kb[(size_t)(k0 + row) * HD + c8]);
            *reinterpret_cast<u16x8*>(&Vs[row][c8]) =
                *reinterpret_cast<const u16x8*>(&Vb[(size_t)row * S + k0 + c8]);
        }
#pragma unroll
        for (int i = 0; i < 2; ++i) {
            const int idx = t + i * 512, row = idx >> 3, c8 = (idx & 7) * 8;
            int4 m0 = *reinterpret_cast<const int4*>(&MASK[b * S + k0 + c8]);
            int4 m1 = *reinterpret_cast<const int4*>(&MASK[b * S + k0 + c8 + 4]);
            u16x8 av;
            if constexpr (ABF16) {
                av = *reinterpret_cast<const u16x8*>(&ABF[hoff + (size_t)(q0 + row) * S + k0 + c8]);
            } else {
                f32x4 a0 = *reinterpret_cast<const f32x4*>(&ALIBI[hoff + (size_t)(q0 + row) * S + k0 + c8]);
                f32x4 a1 = *reinterpret_cast<const f32x4*>(&ALIBI[hoff + (size_t)(q0 + row) * S + k0 + c8 + 4]);
#pragma unroll
                for (int j = 0; j < 4; ++j) {
                    av[j] = f2bf(a0[j] * LOG2E);
                    av[4 + j] = f2bf(a1[j] * LOG2E);
                }
            }
            u16x8 sv;
            sv[0] = m0.x ? NEGBIG : av[0];
            sv[1] = m0.y ? NEGBIG : av[1];
            sv[2] = m0.z ? NEGBIG : av[2];
            sv[3] = m0.w ? NEGBIG : av[3];
            sv[4] = m1.x ? NEGBIG : av[4];
            sv[5] = m1.y ? NEGBIG : av[5];
            sv[6] = m1.z ? NEGBIG : av[6];
            sv[7] = m1.w ? NEGBIG : av[7];
            *reinterpret_cast<u16x8*>(&ALs[row][c8]) = sv;
        }
        __syncthreads();

        f32x4 acc[4] = {};
#pragma unroll
        for (int kk = 0; kk < 2; ++kk)
#pragma unroll
            for (int fn = 0; fn < 4; ++fn) {
                s16x8 kf = *reinterpret_cast<const s16x8*>(&Ks[fn * 16 + lr][kk * 32 + lg * 8]);
                acc[fn] = MFMA_BF16(kf, qf[kk], acc[fn]);   // lane = q-row lr
            }

#pragma unroll
        for (int fn = 0; fn < 4; ++fn) {
            u16x4 alv = *reinterpret_cast<const u16x4*>(&ALs[w * 16 + lr][fn * 16 + lg * 4]);
            f32x4 al;
#pragma unroll
            for (int j = 0; j < 4; ++j) al[j] = bf2f(alv[j]);
            f32x4 sv = acc[fn] * SCALE2 + al;
            f32x4 p;
#pragma unroll
            for (int j = 0; j < 4; ++j) p[j] = fexp2(sv[j]);
            p *= invl;
            __builtin_nontemporal_store(
                p, reinterpret_cast<f32x4*>(arow + k0 + fn * 16 + lg * 4));
            // P overwrites the exact ALs slot this lane just consumed
            u16x4 pb;
#pragma unroll
            for (int j = 0; j < 4; ++j) pb[j] = f2bf_fast(p[j]);
            *reinterpret_cast<u16x4*>(&ALs[w * 16 + lr][fn * 16 + lg * 4]) = pb;
        }

        // PV: same-wave rows of ALs (now P); in-order DS per wave
#pragma unroll
        for (int c = 0; c < 2; ++c) {
            s16x8 pa = *reinterpret_cast<const s16x8*>(&ALs[w * 16 + lr][c * 32 + lg * 8]);
#pragma unroll
            for (int fn = 0; fn < 4; ++fn) {
                s16x8 vf = *reinterpret_cast<const s16x8*>(&Vs[fn * 16 + lr][c * 32 + lg * 8]);
                oacc[fn] = MFMA_BF16(pa, vf, oacc[fn]);
            }
        }
        __syncthreads();
    }

#pragma unroll
    for (int fn = 0; fn < 4; ++fn)
#pragma unroll
        for (int r = 0; r < 4; ++r)
            OUT[(size_t)(b * S + q0 + w * 16 + lg * 4 + r) * D + h * HD + fn * 16 + lr] =
                oacc[fn][r];
}

// ---------------------------------------------------------------------------
extern "C" void kernel_launch(void* const* d_in, const int* in_sizes, int n_in,
                              void* d_out, int out_size, void* d_ws, size_t ws_size,
                              hipStream_t stream) {
    const float* q     = (const float*)d_in[0];
    const float* k     = (const float*)d_in[1];
    const float* v     = (const float*)d_in[2];
    const int*   mask  = (const int*)d_in[3];
    const float* alibi = (const float*)d_in[4];
    const float* Wq    = (const float*)d_in[5];
    const float* Wk    = (const float*)d_in[6];
    const float* Wv    = (const float*)d_in[7];

    float* out = (float*)d_out;                 // [B,S,D]
    float* a   = out + (size_t)B * S * D;       // [B,H,S,S]

    const size_t NH = (size_t)B * H * S * HD;   // 8.4M elems
    unsigned short* qh  = (unsigned short*)d_ws;
    unsigned short* kh  = qh + NH;
    unsigned short* vT  = kh + NH;
    unsigned short* wqt = vT + NH;
    unsigned short* wkt = wqt + (size_t)D * D;
    unsigned short* wvt = wkt + (size_t)D * D;
    unsigned short* qb  = wvt + (size_t)D * D;  // bf16 copies of q,k,v
    unsigned short* kb  = qb + NH;
    unsigned short* vb  = kb + NH;
    float*          invl = (float*)(vb + NH);                     // [B*H*S]
    unsigned short* abf  = (unsigned short*)(invl + (size_t)B * H * S);

    const size_t need_bf16 =
        ((size_t)(abf - qh) + (size_t)H * S * S) * sizeof(unsigned short);
    const bool use_abf16 = ws_size >= need_bf16;

    const dim3 blk(256);

    k_prep<<<dim3(6912), blk, 0, stream>>>(q, k, v, qb, kb, vb,
                                           Wq, Wk, Wv, wqt, wkt, wvt);

    k_projabf<<<dim3(11264), blk, 0, stream>>>(qb, kb, vb, wqt, wkt, wvt,
                                               qh, kh, vT, alibi, abf,
                                               use_abf16 ? 1 : 0);

    if (use_abf16) {
        k_sumexp<true><<<dim3(1024), dim3(512), 0, stream>>>(
            qh, kh, alibi, abf, mask, invl);
        k_attn<true><<<dim3(1024), dim3(512), 0, stream>>>(
            qh, kh, vT, alibi, abf, mask, invl, a, out);
    } else {
        k_sumexp<false><<<dim3(1024), dim3(512), 0, stream>>>(
            qh, kh, alibi, abf, mask, invl);
        k_attn<false><<<dim3(1024), dim3(512), 0, stream>>>(
            qh, kh, vT, alibi, abf, mask, invl, a, out);
    }
}

// Round 18
// 598.373 us; speedup vs baseline: 1.1425x; 1.1425x over previous
//
#include <hip/hip_runtime.h>
#include <hip/hip_bf16.h>
#include <math.h>

constexpr int B  = 4;
constexpr int S  = 2048;
constexpr int D  = 1024;
constexpr int H  = 16;
constexpr int HD = 64;
constexpr float LOG2E  = 1.4426950408889634f;
constexpr float SCALE2 = 0.125f * LOG2E;   // fold 1/sqrt(64) and log2(e)

using f32x4 = __attribute__((ext_vector_type(4))) float;
using s16x8 = __attribute__((ext_vector_type(8))) short;
using u16x8 = __attribute__((ext_vector_type(8))) unsigned short;
using u16x4 = __attribute__((ext_vector_type(4))) unsigned short;

__device__ __forceinline__ unsigned short f2bf(float f) {
    union { float f; unsigned u; } x; x.f = f;
    unsigned r = x.u + 0x7fffu + ((x.u >> 16) & 1u);
    return (unsigned short)(r >> 16);
}
__device__ __forceinline__ unsigned short f2bf_fast(float f) {
    union { float f; unsigned u; } x; x.f = f;
    return (unsigned short)((x.u + 0x8000u) >> 16);
}
__device__ __forceinline__ float bf2f(unsigned short h) {
    union { unsigned u; float f; } x; x.u = ((unsigned)h) << 16;
    return x.f;
}
__device__ __forceinline__ float fexp2(float x) {
#if __has_builtin(__builtin_amdgcn_exp2f)
    return __builtin_amdgcn_exp2f(x);
#else
    return __expf(x * 0.6931471805599453f);
#endif
}

#define MFMA_BF16(Af, Bf, Cf) __builtin_amdgcn_mfma_f32_16x16x32_bf16(Af, Bf, Cf, 0, 0, 0)

// ---------------------------------------------------------------------------
// Merged prep (R16-proven): (a) q/k/v f32->bf16, (b) weight transpose+convert,
// (c) alibi f32->bf16 (log2e-prescaled). All-streaming workload; NT loads on
// dead f32 sources keep L2/L3 reserved for the bf16 products (190 MB).
// Block ranges: [0,6144) cvt, [6144,6912) wt, [6912,15104) abf.
// ---------------------------------------------------------------------------
__global__ __launch_bounds__(256) void k_prep(
    const float* __restrict__ Xq, const float* __restrict__ Xk,
    const float* __restrict__ Xv,
    unsigned short* __restrict__ qb, unsigned short* __restrict__ kb,
    unsigned short* __restrict__ vb,
    const float* __restrict__ Wq, const float* __restrict__ Wk,
    const float* __restrict__ Wv,
    unsigned short* __restrict__ wqt, unsigned short* __restrict__ wkt,
    unsigned short* __restrict__ wvt,
    const float* __restrict__ ALIBI, unsigned short* __restrict__ ABF,
    int do_abf) {
    __shared__ unsigned short T[64][68];
    const int bid = blockIdx.x;
    const int t = threadIdx.x;

    if (bid < 6144) {
        // ---- q/k/v convert ----
        const int op = bid >> 11, xb = bid & 2047;
        const float* X = op == 0 ? Xq : (op == 1 ? Xk : Xv);
        unsigned short* O = op == 0 ? qb : (op == 1 ? kb : vb);
        const size_t N = (size_t)B * S * D;
        const size_t stride = (size_t)2048 * 256 * 8;
        for (size_t i = ((size_t)xb * 256 + t) * 8; i < N; i += stride) {
            f32x4 a0 = __builtin_nontemporal_load(reinterpret_cast<const f32x4*>(&X[i]));
            f32x4 a1 = __builtin_nontemporal_load(reinterpret_cast<const f32x4*>(&X[i + 4]));
            u16x8 o;
#pragma unroll
            for (int j = 0; j < 4; ++j) { o[j] = f2bf(a0[j]); o[4 + j] = f2bf(a1[j]); }
            *reinterpret_cast<u16x8*>(&O[i]) = o;
        }
    } else if (bid < 6912) {
        // ---- weight transpose+convert ----
        const int idx = bid - 6144;
        const int op = idx >> 8, r = idx & 255;
        const float* W = op == 0 ? Wq : (op == 1 ? Wk : Wv);
        unsigned short* Wt = op == 0 ? wqt : (op == 1 ? wkt : wvt);
        const int k0 = (r & 15) * 64, n0 = (r >> 4) * 64;
        {
            const int kr = t >> 4, nc4 = (t & 15) * 4;
            for (int rr = 0; rr < 4; ++rr) {
                const int kk = kr + rr * 16;
                f32x4 wv = __builtin_nontemporal_load(
                    reinterpret_cast<const f32x4*>(&W[(size_t)(k0 + kk) * D + n0 + nc4]));
#pragma unroll
                for (int j = 0; j < 4; ++j) T[nc4 + j][kk] = f2bf(wv[j]);
            }
        }
        __syncthreads();
        {
            const int nr = t >> 4, kc4 = (t & 15) * 4;
            for (int rr = 0; rr < 4; ++rr) {
                const int nn = nr + rr * 16;
                u16x4 o;
#pragma unroll
                for (int j = 0; j < 4; ++j) o[j] = T[nn][kc4 + j];
                *reinterpret_cast<u16x4*>(&Wt[(size_t)(n0 + nn) * D + k0 + kc4]) = o;
            }
        }
    } else {
        // ---- alibi convert (pre-scaled by log2e) ----
        if (!do_abf) return;
        const int idx = bid - 6912;
        const size_t N = (size_t)H * S * S;
        const size_t stride = (size_t)8192 * 256 * 8;
        for (size_t i = ((size_t)idx * 256 + t) * 8; i < N; i += stride) {
            f32x4 a0 = __builtin_nontemporal_load(reinterpret_cast<const f32x4*>(&ALIBI[i]));
            f32x4 a1 = __builtin_nontemporal_load(reinterpret_cast<const f32x4*>(&ALIBI[i + 4]));
            u16x8 o;
#pragma unroll
            for (int j = 0; j < 4; ++j) {
                o[j]     = f2bf(a0[j] * LOG2E);
                o[4 + j] = f2bf(a1[j] * LOG2E);
            }
            *reinterpret_cast<u16x8*>(&ABF[i]) = o;
        }
    }
}

// ---------------------------------------------------------------------------
// All three projections in ONE launch (z: 0=q, 1=k, 2=v-transposed).
// X is bf16. z<2 writes head-split Y; z==2 re-tiles through LDS -> vT.
// ---------------------------------------------------------------------------
__global__ __launch_bounds__(256) void k_proj3(
    const unsigned short* __restrict__ qb, const unsigned short* __restrict__ kb,
    const unsigned short* __restrict__ vb,
    const unsigned short* __restrict__ wqt, const unsigned short* __restrict__ wkt,
    const unsigned short* __restrict__ wvt,
    unsigned short* __restrict__ qh, unsigned short* __restrict__ kh,
    unsigned short* __restrict__ vT) {
    __shared__ alignas(16) unsigned short SM[2][128][72];
    unsigned short (*As)[72] = SM[0];
    unsigned short (*Bs)[72] = SM[1];
    const int op = blockIdx.z;
    const unsigned short* X  = op == 0 ? qb : (op == 1 ? kb : vb);
    const unsigned short* Wt = op == 0 ? wqt : (op == 1 ? wkt : wvt);
    const int bm = blockIdx.y * 128, bn = blockIdx.x * 128;
    const int t = threadIdx.x, w = t >> 6, l = t & 63;
    const int wr = w >> 1, wc = w & 1;
    const int lr = l & 15, lg = l >> 4;
    f32x4 acc[4][4] = {};

    for (int k0 = 0; k0 < D; k0 += 64) {
        for (int i = 0; i < 4; ++i) {
            const int idx = t + i * 256;
            const int row = idx >> 3, c8 = (idx & 7) * 8;
            *reinterpret_cast<u16x8*>(&As[row][c8]) =
                *reinterpret_cast<const u16x8*>(&X[(size_t)(bm + row) * D + k0 + c8]);
            *reinterpret_cast<u16x8*>(&Bs[row][c8]) =
                *reinterpret_cast<const u16x8*>(&Wt[(size_t)(bn + row) * D + k0 + c8]);
        }
        __syncthreads();
#pragma unroll
        for (int kk = 0; kk < 2; ++kk) {
            s16x8 af[4], bf[4];
#pragma unroll
            for (int f = 0; f < 4; ++f) {
                af[f] = *reinterpret_cast<const s16x8*>(&As[wr * 64 + f * 16 + lr][kk * 32 + lg * 8]);
                bf[f] = *reinterpret_cast<const s16x8*>(&Bs[wc * 64 + f * 16 + lr][kk * 32 + lg * 8]);
            }
#pragma unroll
            for (int fm = 0; fm < 4; ++fm)
#pragma unroll
                for (int fn = 0; fn < 4; ++fn)
                    acc[fm][fn] = MFMA_BF16(af[fm], bf[fn], acc[fm][fn]);
        }
        __syncthreads();
    }

    if (op < 2) {
        unsigned short* Y = op == 0 ? qh : kh;
#pragma unroll
        for (int fm = 0; fm < 4; ++fm)
#pragma unroll
            for (int fn = 0; fn < 4; ++fn)
#pragma unroll
                for (int r = 0; r < 4; ++r) {
                    const int m = bm + wr * 64 + fm * 16 + lg * 4 + r;
                    const int n = bn + wc * 64 + fn * 16 + lr;
                    const int b = m >> 11, s = m & (S - 1);
                    const int h = n >> 6, e = n & 63;
                    Y[(((size_t)(b * H + h) * S) + s) * HD + e] = f2bf(acc[fm][fn][r]);
                }
    } else {
        unsigned short (*T)[144] = reinterpret_cast<unsigned short(*)[144]>(&SM[0][0][0]);
#pragma unroll
        for (int fm = 0; fm < 4; ++fm)
#pragma unroll
            for (int fn = 0; fn < 4; ++fn)
#pragma unroll
                for (int r = 0; r < 4; ++r)
                    T[wc * 64 + fn * 16 + lr][wr * 64 + fm * 16 + lg * 4 + r] =
                        f2bf(acc[fm][fn][r]);
        __syncthreads();
        const int b = bm >> 11, s0 = bm & (S - 1);
        for (int it = 0; it < 8; ++it) {
            const int idx = t + it * 256;
            const int row = idx >> 4, c8 = (idx & 15) * 8;
            const int h = (bn + row) >> 6, e = (bn + row) & 63;
            *reinterpret_cast<u16x8*>(&vT[((size_t)(b * H + h) * HD + e) * S + s0 + c8]) =
                *reinterpret_cast<const u16x8*>(&T[row][c8]);
        }
    }
}

// ---------------------------------------------------------------------------
// Pass 1 (swapped QK^T): invl[b,h,q] = 1/sum_k exp2(score2).
// 1024 blocks, XCD-chunked: each XCD owns 8 consecutive bh (K/Q L2-resident).
// ---------------------------------------------------------------------------
template <bool ABF16>
__global__ __launch_bounds__(512, 4) void k_sumexp(
    const unsigned short* __restrict__ QH, const unsigned short* __restrict__ KH,
    const float* __restrict__ ALIBI, const unsigned short* __restrict__ ABF,
    const int* __restrict__ MASK, float* __restrict__ INVL) {
    __shared__ alignas(16) unsigned short Ks[64][72];
    __shared__ alignas(16) unsigned short ALs[128][72];

    const int bid = blockIdx.x;
    const int wg = (bid & 7) * 128 + (bid >> 3);   // XCD-chunked (1024 % 8 == 0)
    const int bh = wg >> 4, b = bh >> 4, h = bh & 15;
    const int q0 = (wg & 15) * 128;
    const int t = threadIdx.x, w = t >> 6, ln = t & 63;
    const int lr = ln & 15, lg = ln >> 4;
    const unsigned short NEGBIG = f2bf(-1e30f);
    const size_t hoff = (size_t)h * S * S;

    const unsigned short* Kb = KH + (size_t)bh * S * HD;

    s16x8 qf[2];
#pragma unroll
    for (int kk = 0; kk < 2; ++kk)
        qf[kk] = *reinterpret_cast<const s16x8*>(
            &QH[((size_t)bh * S + q0 + w * 16 + lr) * HD + kk * 32 + lg * 8]);

    float psum = 0.f;

    for (int k0 = 0; k0 < S; k0 += 64) {
        {
            const int row = t >> 3, c8 = (t & 7) * 8;
            *reinterpret_cast<u16x8*>(&Ks[row][c8]) =
                *reinterpret_cast<const u16x8*>(&Kb[(size_t)(k0 + row) * HD + c8]);
        }
#pragma unroll
        for (int i = 0; i < 2; ++i) {
            const int idx = t + i * 512, row = idx >> 3, c8 = (idx & 7) * 8;
            int4 m0 = *reinterpret_cast<const int4*>(&MASK[b * S + k0 + c8]);
            int4 m1 = *reinterpret_cast<const int4*>(&MASK[b * S + k0 + c8 + 4]);
            u16x8 av;
            if constexpr (ABF16) {
                av = *reinterpret_cast<const u16x8*>(&ABF[hoff + (size_t)(q0 + row) * S + k0 + c8]);
            } else {
                f32x4 a0 = *reinterpret_cast<const f32x4*>(&ALIBI[hoff + (size_t)(q0 + row) * S + k0 + c8]);
                f32x4 a1 = *reinterpret_cast<const f32x4*>(&ALIBI[hoff + (size_t)(q0 + row) * S + k0 + c8 + 4]);
#pragma unroll
                for (int j = 0; j < 4; ++j) {
                    av[j] = f2bf(a0[j] * LOG2E);
                    av[4 + j] = f2bf(a1[j] * LOG2E);
                }
            }
            u16x8 sv;
            sv[0] = m0.x ? NEGBIG : av[0];
            sv[1] = m0.y ? NEGBIG : av[1];
            sv[2] = m0.z ? NEGBIG : av[2];
            sv[3] = m0.w ? NEGBIG : av[3];
            sv[4] = m1.x ? NEGBIG : av[4];
            sv[5] = m1.y ? NEGBIG : av[5];
            sv[6] = m1.z ? NEGBIG : av[6];
            sv[7] = m1.w ? NEGBIG : av[7];
            *reinterpret_cast<u16x8*>(&ALs[row][c8]) = sv;
        }
        __syncthreads();

        f32x4 acc[4] = {};
#pragma unroll
        for (int kk = 0; kk < 2; ++kk)
#pragma unroll
            for (int fn = 0; fn < 4; ++fn) {
                s16x8 kf = *reinterpret_cast<const s16x8*>(&Ks[fn * 16 + lr][kk * 32 + lg * 8]);
                acc[fn] = MFMA_BF16(kf, qf[kk], acc[fn]);   // SWAPPED: lane = q-row lr
            }
#pragma unroll
        for (int fn = 0; fn < 4; ++fn) {
            u16x4 alv = *reinterpret_cast<const u16x4*>(&ALs[w * 16 + lr][fn * 16 + lg * 4]);
            f32x4 al;
#pragma unroll
            for (int j = 0; j < 4; ++j) al[j] = bf2f(alv[j]);
            f32x4 sv = acc[fn] * SCALE2 + al;
            psum += fexp2(sv[0]) + fexp2(sv[1]) + fexp2(sv[2]) + fexp2(sv[3]);
        }
        __syncthreads();
    }

    psum += __shfl_xor(psum, 16, 64);
    psum += __shfl_xor(psum, 32, 64);
    if (lg == 0)
        INVL[(size_t)bh * S + q0 + w * 16 + lr] = 1.0f / psum;
}

// ---------------------------------------------------------------------------
// Pass 2 (swapped QK^T): p -> `a` (f32x4 NT stores from regs) + PV -> out.
// Ps aliases ALs (each slot read+rewritten by the same lane). XCD-chunked.
// ---------------------------------------------------------------------------
template <bool ABF16>
__global__ __launch_bounds__(512, 4) void k_attn(
    const unsigned short* __restrict__ QH, const unsigned short* __restrict__ KH,
    const unsigned short* __restrict__ VT, const float* __restrict__ ALIBI,
    const unsigned short* __restrict__ ABF, const int* __restrict__ MASK,
    const float* __restrict__ INVL, float* __restrict__ Aout,
    float* __restrict__ OUT) {
    __shared__ alignas(16) unsigned short Ks[64][72];
    __shared__ alignas(16) unsigned short Vs[64][72];
    __shared__ alignas(16) unsigned short ALs[128][72];   // alibi tile, then P (aliased)

    const int bid = blockIdx.x;
    const int wg = (bid & 7) * 128 + (bid >> 3);   // XCD-chunked
    const int bh = wg >> 4, b = bh >> 4, h = bh & 15;
    const int q0 = (wg & 15) * 128;
    const int t = threadIdx.x, w = t >> 6, ln = t & 63;
    const int lr = ln & 15, lg = ln >> 4;
    const unsigned short NEGBIG = f2bf(-1e30f);
    const size_t hoff = (size_t)h * S * S;

    const unsigned short* Kb = KH + (size_t)bh * S * HD;
    const unsigned short* Vb = VT + (size_t)bh * HD * S;

    s16x8 qf[2];
#pragma unroll
    for (int kk = 0; kk < 2; ++kk)
        qf[kk] = *reinterpret_cast<const s16x8*>(
            &QH[((size_t)bh * S + q0 + w * 16 + lr) * HD + kk * 32 + lg * 8]);

    const float invl = INVL[(size_t)bh * S + q0 + w * 16 + lr];
    float* arow = Aout + ((size_t)bh * S + q0 + w * 16 + lr) * S;

    f32x4 oacc[4] = {};

    for (int k0 = 0; k0 < S; k0 += 64) {
        {
            const int row = t >> 3, c8 = (t & 7) * 8;
            *reinterpret_cast<u16x8*>(&Ks[row][c8]) =
                *reinterpret_cast<const u16x8*>(&Kb[(size_t)(k0 + row) * HD + c8]);
            *reinterpret_cast<u16x8*>(&Vs[row][c8]) =
                *reinterpret_cast<const u16x8*>(&Vb[(size_t)row * S + k0 + c8]);
        }
#pragma unroll
        for (int i = 0; i < 2; ++i) {
            const int idx = t + i * 512, row = idx >> 3, c8 = (idx & 7) * 8;
            int4 m0 = *reinterpret_cast<const int4*>(&MASK[b * S + k0 + c8]);
            int4 m1 = *reinterpret_cast<const int4*>(&MASK[b * S + k0 + c8 + 4]);
            u16x8 av;
            if constexpr (ABF16) {
                av = *reinterpret_cast<const u16x8*>(&ABF[hoff + (size_t)(q0 + row) * S + k0 + c8]);
            } else {
                f32x4 a0 = *reinterpret_cast<const f32x4*>(&ALIBI[hoff + (size_t)(q0 + row) * S + k0 + c8]);
                f32x4 a1 = *reinterpret_cast<const f32x4*>(&ALIBI[hoff + (size_t)(q0 + row) * S + k0 + c8 + 4]);
#pragma unroll
                for (int j = 0; j < 4; ++j) {
                    av[j] = f2bf(a0[j] * LOG2E);
                    av[4 + j] = f2bf(a1[j] * LOG2E);
                }
            }
            u16x8 sv;
            sv[0] = m0.x ? NEGBIG : av[0];
            sv[1] = m0.y ? NEGBIG : av[1];
            sv[2] = m0.z ? NEGBIG : av[2];
            sv[3] = m0.w ? NEGBIG : av[3];
            sv[4] = m1.x ? NEGBIG : av[4];
            sv[5] = m1.y ? NEGBIG : av[5];
            sv[6] = m1.z ? NEGBIG : av[6];
            sv[7] = m1.w ? NEGBIG : av[7];
            *reinterpret_cast<u16x8*>(&ALs[row][c8]) = sv;
        }
        __syncthreads();

        f32x4 acc[4] = {};
#pragma unroll
        for (int kk = 0; kk < 2; ++kk)
#pragma unroll
            for (int fn = 0; fn < 4; ++fn) {
                s16x8 kf = *reinterpret_cast<const s16x8*>(&Ks[fn * 16 + lr][kk * 32 + lg * 8]);
                acc[fn] = MFMA_BF16(kf, qf[kk], acc[fn]);   // lane = q-row lr
            }

#pragma unroll
        for (int fn = 0; fn < 4; ++fn) {
            u16x4 alv = *reinterpret_cast<const u16x4*>(&ALs[w * 16 + lr][fn * 16 + lg * 4]);
            f32x4 al;
#pragma unroll
            for (int j = 0; j < 4; ++j) al[j] = bf2f(alv[j]);
            f32x4 sv = acc[fn] * SCALE2 + al;
            f32x4 p;
#pragma unroll
            for (int j = 0; j < 4; ++j) p[j] = fexp2(sv[j]);
            p *= invl;
            __builtin_nontemporal_store(
                p, reinterpret_cast<f32x4*>(arow + k0 + fn * 16 + lg * 4));
            // P overwrites the exact ALs slot this lane just consumed
            u16x4 pb;
#pragma unroll
            for (int j = 0; j < 4; ++j) pb[j] = f2bf_fast(p[j]);
            *reinterpret_cast<u16x4*>(&ALs[w * 16 + lr][fn * 16 + lg * 4]) = pb;
        }

        // PV: same-wave rows of ALs (now P); in-order DS per wave
#pragma unroll
        for (int c = 0; c < 2; ++c) {
            s16x8 pa = *reinterpret_cast<const s16x8*>(&ALs[w * 16 + lr][c * 32 + lg * 8]);
#pragma unroll
            for (int fn = 0; fn < 4; ++fn) {
                s16x8 vf = *reinterpret_cast<const s16x8*>(&Vs[fn * 16 + lr][c * 32 + lg * 8]);
                oacc[fn] = MFMA_BF16(pa, vf, oacc[fn]);
            }
        }
        __syncthreads();
    }

#pragma unroll
    for (int fn = 0; fn < 4; ++fn)
#pragma unroll
        for (int r = 0; r < 4; ++r)
            OUT[(size_t)(b * S + q0 + w * 16 + lg * 4 + r) * D + h * HD + fn * 16 + lr] =
                oacc[fn][r];
}

// ---------------------------------------------------------------------------
extern "C" void kernel_launch(void* const* d_in, const int* in_sizes, int n_in,
                              void* d_out, int out_size, void* d_ws, size_t ws_size,
                              hipStream_t stream) {
    const float* q     = (const float*)d_in[0];
    const float* k     = (const float*)d_in[1];
    const float* v     = (const float*)d_in[2];
    const int*   mask  = (const int*)d_in[3];
    const float* alibi = (const float*)d_in[4];
    const float* Wq    = (const float*)d_in[5];
    const float* Wk    = (const float*)d_in[6];
    const float* Wv    = (const float*)d_in[7];

    float* out = (float*)d_out;                 // [B,S,D]
    float* a   = out + (size_t)B * S * D;       // [B,H,S,S]

    const size_t NH = (size_t)B * H * S * HD;   // 8.4M elems
    unsigned short* qh  = (unsigned short*)d_ws;
    unsigned short* kh  = qh + NH;
    unsigned short* vT  = kh + NH;
    unsigned short* wqt = vT + NH;
    unsigned short* wkt = wqt + (size_t)D * D;
    unsigned short* wvt = wkt + (size_t)D * D;
    unsigned short* qb  = wvt + (size_t)D * D;  // bf16 copies of q,k,v
    unsigned short* kb  = qb + NH;
    unsigned short* vb  = kb + NH;
    float*          invl = (float*)(vb + NH);                     // [B*H*S]
    unsigned short* abf  = (unsigned short*)(invl + (size_t)B * H * S);

    const size_t need_bf16 =
        ((size_t)(abf - qh) + (size_t)H * S * S) * sizeof(unsigned short);
    const bool use_abf16 = ws_size >= need_bf16;

    const dim3 blk(256);

    k_prep<<<dim3(15104), blk, 0, stream>>>(q, k, v, qb, kb, vb,
                                            Wq, Wk, Wv, wqt, wkt, wvt,
                                            alibi, abf, use_abf16 ? 1 : 0);

    k_proj3<<<dim3(D / 128, (B * S) / 128, 3), blk, 0, stream>>>(
        qb, kb, vb, wqt, wkt, wvt, qh, kh, vT);

    if (use_abf16) {
        k_sumexp<true><<<dim3(1024), dim3(512), 0, stream>>>(
            qh, kh, alibi, abf, mask, invl);
        k_attn<true><<<dim3(1024), dim3(512), 0, stream>>>(
            qh, kh, vT, alibi, abf, mask, invl, a, out);
    } else {
        k_sumexp<false><<<dim3(1024), dim3(512), 0, stream>>>(
            qh, kh, alibi, abf, mask, invl);
        k_attn<false><<<dim3(1024), dim3(512), 0, stream>>>(
            qh, kh, vT, alibi, abf, mask, invl, a, out);
    }
}